// Round 10
// baseline (1231.538 us; speedup 1.0000x reference)
//
#include <hip/hip_runtime.h>

// GCN 3-layer. Two-level dst sort: scatterA -> 2048-node buckets (134
// entries/tile/bucket => 64B lines fill in ~1/8 tile => full-line write-back;
// R8/R9 proved 1-line-per-tile buckets thrash regardless of grid size),
// then scatterBB splits each 2048-bucket into 8 256-buckets with ballot-
// aggregated cursors (sequential run appends). sortbuild does in-LDS counting
// sort per 256-bucket + dinv/z1; layers do wave-segmented reduction (shfl
// scan) with ~3 LDS atomic tail-writes per 64-edge group (R7->R8 win).
// Math per layer (input u): z = u*dinv; s_i = sum_{e:dst=i} z[src_e];
//   out_i = (dinv_i*(s_i + z_i)) @ W + b   (self-loop folds into s+z).
// pkA = (dst&2047)|(src<<11); pk32 = (dst&255)|(src<<8). N < 2^19.

#define TPB 256
#define T_TILE 32768
#define NPB 256
#define NPB_BITS 8
#define NPB1_BITS 11
#define ELDS_CAP 10752   // mean 256-bucket 8188 edges, +28 sigma

// ---- tile histogram at 256-node granularity; also emit 2048-level sums ----
__global__ void tilecount(const int* __restrict__ dst, int* __restrict__ cnt1954,
                          int* __restrict__ cnt245, int ntB, int E, int B256, int B1) {
    __shared__ int hist[2048];
    int blk = blockIdx.x, tid = threadIdx.x;
    #pragma unroll
    for (int j = 0; j < 8; ++j) hist[tid + j * 256] = 0;
    __syncthreads();
    int base = blk * T_TILE;
    #pragma unroll 8
    for (int it = 0; it < T_TILE / 256; ++it) {
        int e = base + it * 256 + tid;
        if (e < E) atomicAdd(&hist[((unsigned)dst[e]) >> NPB_BITS], 1);
    }
    __syncthreads();
    for (int l = tid; l < B256; l += 256)
        cnt1954[(size_t)l * ntB + blk] = hist[l];
    if (tid < B1) {
        int s = 0;
        #pragma unroll
        for (int j = 0; j < 8; ++j) s += hist[tid * 8 + j];
        cnt245[(size_t)tid * ntB + blk] = s;
    }
}

// ---- 3-kernel exclusive scan over data[len] (in-place), 1024 elems/block ----
__global__ void scan_k1(const int* __restrict__ data, int* __restrict__ bsum, int len) {
    __shared__ int lds[TPB];
    int b = blockIdx.x, t = threadIdx.x;
    int base = b * 1024 + t * 4;
    int s = 0;
    #pragma unroll
    for (int j = 0; j < 4; ++j) { int i = base + j; if (i < len) s += data[i]; }
    lds[t] = s; __syncthreads();
    for (int off = 128; off > 0; off >>= 1) {
        if (t < off) lds[t] += lds[t + off];
        __syncthreads();
    }
    if (t == 0) bsum[b] = lds[0];
}

__global__ void scan_k2(int* __restrict__ bsum, int NB) {
    __shared__ int lds[1024];
    int t = threadIdx.x;
    int v = (t < NB) ? bsum[t] : 0;
    lds[t] = v; __syncthreads();
    for (int off = 1; off < 1024; off <<= 1) {
        int add = (t >= off) ? lds[t - off] : 0;
        __syncthreads();
        lds[t] += add;
        __syncthreads();
    }
    if (t < NB) bsum[t] = lds[t] - v;  // exclusive
}

__global__ void scan_k3(int* __restrict__ data, const int* __restrict__ bsum, int len) {
    __shared__ int lds[TPB];
    int b = blockIdx.x, t = threadIdx.x;
    int base = b * 1024 + t * 4;
    int v[4]; int s = 0;
    #pragma unroll
    for (int j = 0; j < 4; ++j) { int i = base + j; v[j] = (i < len) ? data[i] : 0; s += v[j]; }
    int orig = s;
    lds[t] = s; __syncthreads();
    for (int off = 1; off < 256; off <<= 1) {
        int add = (t >= off) ? lds[t - off] : 0;
        __syncthreads();
        lds[t] += add;
        __syncthreads();
    }
    int run = bsum[b] + lds[t] - orig;
    #pragma unroll
    for (int j = 0; j < 4; ++j) {
        int i = base + j;
        if (i < len) { data[i] = run; run += v[j]; }
    }
}

// ---- per-256-bucket totals (column sum over tiles) + 1-block scan -> baseB ----
__global__ void colsum(const int* __restrict__ cnt1954, int* __restrict__ tot,
                       int ntB, int B256) {
    int l = blockIdx.x * blockDim.x + threadIdx.x;
    if (l < B256) {
        const int* row = cnt1954 + (size_t)l * ntB;
        int s = 0;
        for (int t = 0; t < ntB; ++t) s += row[t];
        tot[l] = s;
    }
}

__global__ void __launch_bounds__(1024)
scanB(const int* __restrict__ tot, int* __restrict__ baseB, int B256, int E) {
    __shared__ int tmp[1024];
    int t = threadIdx.x;
    int i0 = 2 * t, i1 = 2 * t + 1;
    int v0 = (i0 < B256) ? tot[i0] : 0;
    int v1 = (i1 < B256) ? tot[i1] : 0;
    int s = v0 + v1;
    tmp[t] = s; __syncthreads();
    for (int o = 1; o < 1024; o <<= 1) {
        int a = (t >= o) ? tmp[t - o] : 0;
        __syncthreads();
        tmp[t] += a;
        __syncthreads();
    }
    int excl = tmp[t] - s;
    if (i0 < B256) baseB[i0] = excl;
    if (i1 < B256) baseB[i1] = excl + v0;
    if (t == 0) baseB[B256] = E;
}

// ---- level 1: scatter into 2048-node buckets (full grid, clean lines) ----
__global__ void scatterA(const int* __restrict__ dst, const int* __restrict__ src,
                         const int* __restrict__ cnt245, unsigned* __restrict__ pkA,
                         int ntB, int E, int B1) {
    __shared__ int basec[256];
    int tile = blockIdx.x, tid = threadIdx.x;
    if (tid < B1) basec[tid] = cnt245[(size_t)tid * ntB + tile];
    __syncthreads();
    int ebase = tile * T_TILE;
    #pragma unroll 8
    for (int it = 0; it < T_TILE / 256; ++it) {
        int e = ebase + it * 256 + tid;
        if (e < E) {
            unsigned d = (unsigned)dst[e];
            unsigned s = (unsigned)src[e];
            int pos = atomicAdd(&basec[d >> NPB1_BITS], 1);
            pkA[pos] = (d & ((1u << NPB1_BITS) - 1u)) | (s << NPB1_BITS);
        }
    }
}

// ---- level 2: split each 2048-bucket into 8 256-buckets (ballot cursors) ----
__global__ void scatterBB(const unsigned* __restrict__ pkA, const int* __restrict__ baseB,
                          unsigned* __restrict__ pk32, int B256) {
    __shared__ int cur[8];
    int b1 = blockIdx.x, tid = threadIdx.x;
    int sb0 = 8 * b1;
    int nsub = B256 - sb0; if (nsub > 8) nsub = 8;
    if (tid < nsub) cur[tid] = baseB[sb0 + tid];
    __syncthreads();
    int rbeg = baseB[sb0], rend = baseB[sb0 + nsub];
    int lane = tid & 63;
    unsigned long long mlt = (1ull << lane) - 1ull;
    for (int k0 = rbeg; k0 < rend; k0 += 256) {
        int k = k0 + tid;
        bool valid = (k < rend);
        unsigned p = valid ? pkA[k] : 0u;
        int sub = valid ? (int)((p & 2047u) >> NPB_BITS) : 8;
        unsigned out = (p & (NPB - 1u)) | ((p >> NPB1_BITS) << NPB_BITS);
        #pragma unroll
        for (int s = 0; s < 8; ++s) {
            unsigned long long m = __ballot(sub == s);
            if (m == 0ull) continue;
            int leader = (int)__ffsll((unsigned long long)m) - 1;
            int old = 0;
            if (lane == leader) old = atomicAdd(&cur[s], __popcll(m));
            old = __shfl(old, leader, 64);
            if (sub == s) pk32[old + __popcll(m & mlt)] = out;
        }
    }
}

// ---- per-256-bucket in-LDS counting sort + dinv/z1 ----
__global__ void __launch_bounds__(256)
sortbuild(const int* __restrict__ baseB_, unsigned* __restrict__ pk,
          const float* __restrict__ x, float* __restrict__ dinv,
          float* __restrict__ z1, int N) {
    __shared__ int cnt[NPB];
    __shared__ int tmp[NPB];
    __shared__ int cur[NPB];
    __shared__ unsigned eb[ELDS_CAP];
    int b = blockIdx.x, tid = threadIdx.x;
    int base = baseB_[b], n = baseB_[b + 1] - base;
    cnt[tid] = 0;
    __syncthreads();
    int k0 = 0;
    for (; k0 + 2048 <= n; k0 += 2048) {
        unsigned p[8];
        #pragma unroll
        for (int u = 0; u < 8; ++u) p[u] = pk[base + k0 + tid + u * 256];
        #pragma unroll
        for (int u = 0; u < 8; ++u) atomicAdd(&cnt[p[u] & (NPB - 1u)], 1);
    }
    for (int k = k0 + tid; k < n; k += 256)
        atomicAdd(&cnt[pk[base + k] & (NPB - 1u)], 1);
    __syncthreads();
    int c = cnt[tid];
    tmp[tid] = c; __syncthreads();
    for (int o = 1; o < 256; o <<= 1) {
        int a = (tid >= o) ? tmp[tid - o] : 0;
        __syncthreads();
        tmp[tid] += a;
        __syncthreads();
    }
    cur[tid] = tmp[tid] - c;  // exclusive prefix
    int i = (b << NPB_BITS) + tid;
    if (i < N) {
        float di = rsqrtf((float)c + 1.0f);
        dinv[i] = di;
        float2 xv = ((const float2*)x)[i];
        ((float2*)z1)[i] = make_float2(xv.x * di, xv.y * di);
    }
    __syncthreads();
    if (n <= ELDS_CAP) {
        k0 = 0;
        for (; k0 + 2048 <= n; k0 += 2048) {
            unsigned p[8];
            #pragma unroll
            for (int u = 0; u < 8; ++u) p[u] = pk[base + k0 + tid + u * 256];
            #pragma unroll
            for (int u = 0; u < 8; ++u) {
                int pos = atomicAdd(&cur[p[u] & (NPB - 1u)], 1);
                eb[pos] = p[u];
            }
        }
        for (int k = k0 + tid; k < n; k += 256) {
            unsigned p = pk[base + k];
            int pos = atomicAdd(&cur[p & (NPB - 1u)], 1);
            eb[pos] = p;
        }
        __syncthreads();
        for (int k = tid; k < n; k += 256) pk[base + k] = eb[k];
    }
    // else: bucket stays unsorted -- seg-scan layers remain correct.
}

// ---------------- layers: wave-segmented reduction ----------------

__global__ void __launch_bounds__(256)
layer1(const int* __restrict__ baseB_, const unsigned* __restrict__ pk,
       const float* __restrict__ z1, const float* __restrict__ W1,
       const float* __restrict__ b1, const float* __restrict__ dinv,
       float* __restrict__ z2, int N) {
    __shared__ float acc[NPB * 3];
    int b = blockIdx.x, tid = threadIdx.x;
    int base = baseB_[b], n = baseB_[b + 1] - base;
    #pragma unroll
    for (int j = 0; j < 3; ++j) acc[tid + j * 256] = 0.f;
    __syncthreads();
    const float2* z = (const float2*)z1;
    int lane = tid & 63, wv = tid >> 6;
    int G = (n + 63) >> 6;
    for (int g = wv; g < G; g += 4) {
        int k = (g << 6) + lane;
        int d; float s0, s1;
        if (k < n) {
            unsigned p = pk[base + k];
            d = (int)(p & (NPB - 1u));
            float2 v = z[p >> NPB_BITS];
            s0 = v.x; s1 = v.y;
        } else { d = NPB; s0 = 0.f; s1 = 0.f; }
        int dp = __shfl_up(d, 1);
        unsigned f = (lane == 0 || d != dp) ? 1u : 0u;
        #pragma unroll
        for (int o = 1; o < 64; o <<= 1) {
            float t0 = __shfl_up(s0, o), t1 = __shfl_up(s1, o);
            unsigned fu = __shfl_up(f, o);
            if (lane >= o) { if (!f) { s0 += t0; s1 += t1; } f |= fu; }
        }
        int dn = __shfl_down(d, 1);
        bool tail = (lane == 63) || (d != dn);
        if (tail && d < NPB) {
            atomicAdd(&acc[d * 3 + 0], s0);
            atomicAdd(&acc[d * 3 + 1], s1);
        }
    }
    __syncthreads();
    int i = (b << NPB_BITS) + tid;
    if (i < N) {
        float di = dinv[i];
        float2 zi = z[i];
        float g0 = di * (acc[tid * 3 + 0] + zi.x);
        float g1 = di * (acc[tid * 3 + 1] + zi.y);
        float4 o;
        o.x = di * tanhf(fmaf(g0, W1[0], fmaf(g1, W1[4], b1[0])));
        o.y = di * tanhf(fmaf(g0, W1[1], fmaf(g1, W1[5], b1[1])));
        o.z = di * tanhf(fmaf(g0, W1[2], fmaf(g1, W1[6], b1[2])));
        o.w = di * tanhf(fmaf(g0, W1[3], fmaf(g1, W1[7], b1[3])));
        ((float4*)z2)[i] = o;
    }
}

__global__ void __launch_bounds__(256)
layer2(const int* __restrict__ baseB_, const unsigned* __restrict__ pk,
       const float* __restrict__ z2, const float* __restrict__ W2,
       const float* __restrict__ b2, const float* __restrict__ W3,
       const float* __restrict__ dinv, float* __restrict__ z3, int N) {
    __shared__ float acc[NPB * 5];
    int b = blockIdx.x, tid = threadIdx.x;
    int base = baseB_[b], n = baseB_[b + 1] - base;
    #pragma unroll
    for (int j = 0; j < 5; ++j) acc[tid + j * 256] = 0.f;
    __syncthreads();
    const float4* z = (const float4*)z2;
    int lane = tid & 63, wv = tid >> 6;
    int G = (n + 63) >> 6;
    for (int g = wv; g < G; g += 4) {
        int k = (g << 6) + lane;
        int d; float s0, s1, s2, s3;
        if (k < n) {
            unsigned p = pk[base + k];
            d = (int)(p & (NPB - 1u));
            float4 v = z[p >> NPB_BITS];
            s0 = v.x; s1 = v.y; s2 = v.z; s3 = v.w;
        } else { d = NPB; s0 = s1 = s2 = s3 = 0.f; }
        int dp = __shfl_up(d, 1);
        unsigned f = (lane == 0 || d != dp) ? 1u : 0u;
        #pragma unroll
        for (int o = 1; o < 64; o <<= 1) {
            float t0 = __shfl_up(s0, o), t1 = __shfl_up(s1, o);
            float t2 = __shfl_up(s2, o), t3 = __shfl_up(s3, o);
            unsigned fu = __shfl_up(f, o);
            if (lane >= o) {
                if (!f) { s0 += t0; s1 += t1; s2 += t2; s3 += t3; }
                f |= fu;
            }
        }
        int dn = __shfl_down(d, 1);
        bool tail = (lane == 63) || (d != dn);
        if (tail && d < NPB) {
            atomicAdd(&acc[d * 5 + 0], s0);
            atomicAdd(&acc[d * 5 + 1], s1);
            atomicAdd(&acc[d * 5 + 2], s2);
            atomicAdd(&acc[d * 5 + 3], s3);
        }
    }
    __syncthreads();
    int i = (b << NPB_BITS) + tid;
    if (i < N) {
        float di = dinv[i];
        float4 zi = z[i];
        float g0 = di * (acc[tid * 5 + 0] + zi.x);
        float g1 = di * (acc[tid * 5 + 1] + zi.y);
        float g2 = di * (acc[tid * 5 + 2] + zi.z);
        float g3 = di * (acc[tid * 5 + 3] + zi.w);
        float h[4];
        #pragma unroll
        for (int c = 0; c < 4; ++c)
            h[c] = tanhf(b2[c] + g0 * W2[c] + g1 * W2[4 + c] + g2 * W2[8 + c] + g3 * W2[12 + c]);
        float v0 = h[0] * W3[0] + h[1] * W3[2] + h[2] * W3[4] + h[3] * W3[6];
        float v1 = h[0] * W3[1] + h[1] * W3[3] + h[2] * W3[5] + h[3] * W3[7];
        ((float2*)z3)[i] = make_float2(v0 * di, v1 * di);
    }
}

__global__ void __launch_bounds__(256)
layer3(const int* __restrict__ baseB_, const unsigned* __restrict__ pk,
       const float* __restrict__ z3, const float* __restrict__ b3,
       const float* __restrict__ dinv, float* __restrict__ out, int N) {
    __shared__ float acc[NPB * 3];
    int b = blockIdx.x, tid = threadIdx.x;
    int base = baseB_[b], n = baseB_[b + 1] - base;
    #pragma unroll
    for (int j = 0; j < 3; ++j) acc[tid + j * 256] = 0.f;
    __syncthreads();
    const float2* z = (const float2*)z3;
    int lane = tid & 63, wv = tid >> 6;
    int G = (n + 63) >> 6;
    for (int g = wv; g < G; g += 4) {
        int k = (g << 6) + lane;
        int d; float s0, s1;
        if (k < n) {
            unsigned p = pk[base + k];
            d = (int)(p & (NPB - 1u));
            float2 v = z[p >> NPB_BITS];
            s0 = v.x; s1 = v.y;
        } else { d = NPB; s0 = 0.f; s1 = 0.f; }
        int dp = __shfl_up(d, 1);
        unsigned f = (lane == 0 || d != dp) ? 1u : 0u;
        #pragma unroll
        for (int o = 1; o < 64; o <<= 1) {
            float t0 = __shfl_up(s0, o), t1 = __shfl_up(s1, o);
            unsigned fu = __shfl_up(f, o);
            if (lane >= o) { if (!f) { s0 += t0; s1 += t1; } f |= fu; }
        }
        int dn = __shfl_down(d, 1);
        bool tail = (lane == 63) || (d != dn);
        if (tail && d < NPB) {
            atomicAdd(&acc[d * 3 + 0], s0);
            atomicAdd(&acc[d * 3 + 1], s1);
        }
    }
    __syncthreads();
    int i = (b << NPB_BITS) + tid;
    if (i < N) {
        float di = dinv[i];
        float2 zi = z[i];
        ((float2*)out)[i] = make_float2(fmaf(di, acc[tid * 3 + 0] + zi.x, b3[0]),
                                        fmaf(di, acc[tid * 3 + 1] + zi.y, b3[1]));
    }
}

extern "C" void kernel_launch(void* const* d_in, const int* in_sizes, int n_in,
                              void* d_out, int out_size, void* d_ws, size_t ws_size,
                              hipStream_t stream) {
    const float* x  = (const float*)d_in[0];
    const int*   ei = (const int*)d_in[1];
    const float* W1 = (const float*)d_in[2];
    const float* b1 = (const float*)d_in[3];
    const float* W2 = (const float*)d_in[4];
    const float* b2 = (const float*)d_in[5];
    const float* W3 = (const float*)d_in[6];
    const float* b3 = (const float*)d_in[7];
    float* out = (float*)d_out;

    const int N = in_sizes[0] / 2;
    const int E = in_sizes[1] / 2;
    const int* src = ei;
    const int* dst = ei + E;

    const int B256 = (N + NPB - 1) >> NPB_BITS;          // 1954
    const int B1   = (N + (1 << NPB1_BITS) - 1) >> NPB1_BITS;  // 245
    const int ntB  = (E + T_TILE - 1) / T_TILE;          // 489
    const int mlen2 = B1 * ntB;                          // ~120K
    const int NB2 = (mlen2 + 1023) / 1024;               // ~118

    // ws layout (256B-aligned). Overlays: cnt1954 in z2 (colsum reads before
    // layer1 writes z2); cnt245 in z3 (scatterA reads before layer2 writes z3).
    auto align = [](size_t o) { return (o + 255) & ~(size_t)255; };
    char* wbase = (char*)d_ws;
    size_t off = 0;
    float*    dinv  = (float*)(wbase + off);    off = align(off + (size_t)N * 4);
    float*    z1    = (float*)(wbase + off);    off = align(off + (size_t)2 * N * 4);
    float*    z2    = (float*)(wbase + off);    off = align(off + (size_t)4 * N * 4);
    float*    z3    = (float*)(wbase + off);    off = align(off + (size_t)2 * N * 4);
    int*      bsum  = (int*)(wbase + off);      off = align(off + (size_t)1024 * 4);
    int*      tot   = (int*)(wbase + off);      off = align(off + (size_t)B256 * 4);
    int*      baseB = (int*)(wbase + off);      off = align(off + (size_t)(B256 + 1) * 4);
    unsigned* pkA   = (unsigned*)(wbase + off); off = align(off + (size_t)E * 4);
    unsigned* pk32  = (unsigned*)(wbase + off); off = align(off + (size_t)E * 4);
    int*      cnt1954 = (int*)z2;               // 3.74MB <= 8MB
    int*      cnt245  = (int*)z3;               // 0.46MB <= 4MB

    dim3 blk(TPB);
    tilecount<<<dim3(ntB), blk, 0, stream>>>(dst, cnt1954, cnt245, ntB, E, B256, B1);
    scan_k1<<<dim3(NB2), blk, 0, stream>>>(cnt245, bsum, mlen2);
    scan_k2<<<dim3(1), dim3(1024), 0, stream>>>(bsum, NB2);
    scan_k3<<<dim3(NB2), blk, 0, stream>>>(cnt245, bsum, mlen2);
    colsum<<<dim3((B256 + 255) / 256), blk, 0, stream>>>(cnt1954, tot, ntB, B256);
    scanB<<<dim3(1), dim3(1024), 0, stream>>>(tot, baseB, B256, E);
    scatterA<<<dim3(ntB), blk, 0, stream>>>(dst, src, cnt245, pkA, ntB, E, B1);
    scatterBB<<<dim3(B1), blk, 0, stream>>>(pkA, baseB, pk32, B256);
    sortbuild<<<dim3(B256), blk, 0, stream>>>(baseB, pk32, x, dinv, z1, N);
    layer1<<<dim3(B256), blk, 0, stream>>>(baseB, pk32, z1, W1, b1, dinv, z2, N);
    layer2<<<dim3(B256), blk, 0, stream>>>(baseB, pk32, z2, W2, b2, W3, dinv, z3, N);
    layer3<<<dim3(B256), blk, 0, stream>>>(baseB, pk32, z3, b3, dinv, out, N);
}

// Round 11
// 1007.850 us; speedup vs baseline: 1.2219x; 1.2219x over previous
//
#include <hip/hip_runtime.h>

// GCN 3-layer via radix CSR build + unrolled gather layers (R3-style).
// Math per layer (input u): z = u*dinv; s_i = sum_{e:dst=i} z[src_e];
//   out_i = (dinv_i*(s_i + z_i)) @ W + b   (self-loop folds into s+z).
// Build: tilecount(1024-node buckets, 489x489 matrix) -> exscan -> scatterD
// (256 blocks x 2 consecutive tiles: 489 buckets x 32 blk/XCD x 64B ~= 1MB
// dirty cursor lines < L2 -> full-line write-back; R8/R9/R10 established the
// <=1MB rule) -> sortbuild (block-per-bucket in-LDS counting sort, 136KB edge
// stage, coalesced csr writeback + rowptr/dinv/z1 fused). Layers: R3-proven
// thread-per-node gather, 16/8-deep unrolled (zero atomics, full occupancy).
// pk = (dst&1023)|(src<<10) (29 bits, N < 2^19).

#define TPB 256
#define T_TILE 32768
#define NPB 1024
#define NPB_BITS 10
#define EB_CAP 34048     // mean bucket 32.7K edges, +7 sigma

// ---------------- build: count, scan, scatter, node-sort ----------------

__global__ void tilecount(const int* __restrict__ dst, int* __restrict__ cntD,
                          int ntB, int E, int B) {
    __shared__ int hist[512];
    int blk = blockIdx.x, tid = threadIdx.x;
    hist[tid] = 0; hist[tid + 256] = 0;
    __syncthreads();
    int base = blk * T_TILE;
    #pragma unroll 8
    for (int it = 0; it < T_TILE / 256; ++it) {
        int e = base + it * 256 + tid;
        if (e < E) atomicAdd(&hist[((unsigned)dst[e]) >> NPB_BITS], 1);
    }
    __syncthreads();
    for (int l = tid; l < B; l += 256)
        cntD[(size_t)l * ntB + blk] = hist[l];
}

// ---- 3-kernel exclusive scan over data[len] (in-place), 1024 elems/block ----
__global__ void scan_k1(const int* __restrict__ data, int* __restrict__ bsum, int len) {
    __shared__ int lds[TPB];
    int b = blockIdx.x, t = threadIdx.x;
    int base = b * 1024 + t * 4;
    int s = 0;
    #pragma unroll
    for (int j = 0; j < 4; ++j) { int i = base + j; if (i < len) s += data[i]; }
    lds[t] = s; __syncthreads();
    for (int off = 128; off > 0; off >>= 1) {
        if (t < off) lds[t] += lds[t + off];
        __syncthreads();
    }
    if (t == 0) bsum[b] = lds[0];
}

__global__ void scan_k2(int* __restrict__ bsum, int NB) {
    __shared__ int lds[1024];
    int t = threadIdx.x;
    int v = (t < NB) ? bsum[t] : 0;
    lds[t] = v; __syncthreads();
    for (int off = 1; off < 1024; off <<= 1) {
        int add = (t >= off) ? lds[t - off] : 0;
        __syncthreads();
        lds[t] += add;
        __syncthreads();
    }
    if (t < NB) bsum[t] = lds[t] - v;  // exclusive
}

__global__ void scan_k3(int* __restrict__ data, const int* __restrict__ bsum, int len) {
    __shared__ int lds[TPB];
    int b = blockIdx.x, t = threadIdx.x;
    int base = b * 1024 + t * 4;
    int v[4]; int s = 0;
    #pragma unroll
    for (int j = 0; j < 4; ++j) { int i = base + j; v[j] = (i < len) ? data[i] : 0; s += v[j]; }
    int orig = s;
    lds[t] = s; __syncthreads();
    for (int off = 1; off < 256; off <<= 1) {
        int add = (t >= off) ? lds[t - off] : 0;
        __syncthreads();
        lds[t] += add;
        __syncthreads();
    }
    int run = bsum[b] + lds[t] - orig;
    #pragma unroll
    for (int j = 0; j < 4; ++j) {
        int i = base + j;
        if (i < len) { data[i] = run; run += v[j]; }
    }
}

__global__ void extract_bases(const int* __restrict__ cntD, int ntB, int B,
                              int* __restrict__ baseD, int E) {
    int t = threadIdx.x;
    for (int l = t; l < B; l += blockDim.x) baseD[l] = cntD[(size_t)l * ntB];
    if (t == 0) baseD[B] = E;
}

// 256 blocks x 2 CONSECUTIVE tiles: dirty cursor set ~1MB/XCD -> clean.
__global__ void scatterD(const int* __restrict__ dst, const int* __restrict__ src,
                         const int* __restrict__ cntD, unsigned* __restrict__ pk,
                         int ntB, int E, int B) {
    __shared__ int basec[512];
    int tid = threadIdx.x;
    int t0 = blockIdx.x * 2;
    for (int tt = 0; tt < 2; ++tt) {
        int tile = t0 + tt;
        if (tile >= ntB) return;
        for (int l = tid; l < B; l += 256)
            basec[l] = cntD[(size_t)l * ntB + tile];
        __syncthreads();
        int ebase = tile * T_TILE;
        #pragma unroll 8
        for (int it = 0; it < T_TILE / 256; ++it) {
            int e = ebase + it * 256 + tid;
            if (e < E) {
                unsigned d = (unsigned)dst[e];
                unsigned s = (unsigned)src[e];
                int pos = atomicAdd(&basec[d >> NPB_BITS], 1);
                pk[pos] = (d & (NPB - 1u)) | (s << NPB_BITS);
            }
        }
        __syncthreads();  // cursors settled before next tile reload
    }
}

// Block-per-bucket: LDS count per node, scan -> rowptr/dinv/z1, stage sorted
// edges in LDS, coalesced csr writeback (csr = src per node, contiguous).
__global__ void __launch_bounds__(256)
sortbuild(const int* __restrict__ baseD, const unsigned* __restrict__ pk,
          const float* __restrict__ x, int* __restrict__ rowptr,
          float* __restrict__ dinv, float* __restrict__ z1,
          unsigned* __restrict__ csr, int N, int B) {
    __shared__ int cnt[NPB];
    __shared__ int tmp[256];
    __shared__ int cur[NPB];
    __shared__ unsigned eb[EB_CAP];
    int b = blockIdx.x, tid = threadIdx.x;
    int base = baseD[b], n = baseD[b + 1] - base;
    #pragma unroll
    for (int j = 0; j < 4; ++j) cnt[tid + j * 256] = 0;
    __syncthreads();
    int k0 = 0;
    for (; k0 + 2048 <= n; k0 += 2048) {
        unsigned p[8];
        #pragma unroll
        for (int u = 0; u < 8; ++u) p[u] = pk[base + k0 + tid + u * 256];
        #pragma unroll
        for (int u = 0; u < 8; ++u) atomicAdd(&cnt[p[u] & (NPB - 1u)], 1);
    }
    for (int k = k0 + tid; k < n; k += 256)
        atomicAdd(&cnt[pk[base + k] & (NPB - 1u)], 1);
    __syncthreads();
    int c[4]; int s = 0;
    #pragma unroll
    for (int j = 0; j < 4; ++j) { c[j] = cnt[4 * tid + j]; s += c[j]; }
    tmp[tid] = s; __syncthreads();
    for (int o = 1; o < 256; o <<= 1) {
        int a = (tid >= o) ? tmp[tid - o] : 0;
        __syncthreads();
        tmp[tid] += a;
        __syncthreads();
    }
    int run = tmp[tid] - s;  // exclusive prefix (bucket-local)
    int i0 = (b << NPB_BITS) + 4 * tid;
    #pragma unroll
    for (int j = 0; j < 4; ++j) {
        int i = i0 + j;
        if (i < N) {
            rowptr[i] = base + run;
            float di = rsqrtf((float)c[j] + 1.0f);
            dinv[i] = di;
            float2 xv = ((const float2*)x)[i];
            ((float2*)z1)[i] = make_float2(xv.x * di, xv.y * di);
        }
        cur[4 * tid + j] = run;  // local cursor
        run += c[j];
    }
    if (b == B - 1 && tid == 0) rowptr[N] = (int)baseD[B];
    __syncthreads();
    if (n <= EB_CAP) {
        k0 = 0;
        for (; k0 + 2048 <= n; k0 += 2048) {
            unsigned p[8];
            #pragma unroll
            for (int u = 0; u < 8; ++u) p[u] = pk[base + k0 + tid + u * 256];
            #pragma unroll
            for (int u = 0; u < 8; ++u) {
                int pos = atomicAdd(&cur[p[u] & (NPB - 1u)], 1);
                eb[pos] = p[u];
            }
        }
        for (int k = k0 + tid; k < n; k += 256) {
            unsigned p = pk[base + k];
            int pos = atomicAdd(&cur[p & (NPB - 1u)], 1);
            eb[pos] = p;
        }
        __syncthreads();
        for (int k = tid; k < n; k += 256) csr[base + k] = eb[k] >> NPB_BITS;
    } else {
        // rare overflow: direct global placement (slow but correct)
        for (int k = tid; k < n; k += 256) {
            unsigned p = pk[base + k];
            int pos = atomicAdd(&cur[p & (NPB - 1u)], 1);
            csr[base + pos] = p >> NPB_BITS;
        }
    }
}

// ---------------- GCN layers (R3-proven unrolled gathers) ----------------

__global__ void gcn1(const int* __restrict__ rowptr, const unsigned* __restrict__ csr,
                     const float* __restrict__ z1, const float* __restrict__ W1,
                     const float* __restrict__ b1, const float* __restrict__ dinv,
                     float* __restrict__ z2, int N) {
    int i = blockIdx.x * blockDim.x + threadIdx.x;
    if (i >= N) return;
    int r0 = rowptr[i], r1 = rowptr[i + 1];
    float2 zi = ((const float2*)z1)[i];
    float a0 = zi.x, a1 = zi.y;
    const float2* z = (const float2*)z1;
    int k = r0;
    for (; k + 16 <= r1; k += 16) {
        unsigned j[16];
        #pragma unroll
        for (int u = 0; u < 16; ++u) j[u] = csr[k + u];
        float2 v[16];
        #pragma unroll
        for (int u = 0; u < 16; ++u) v[u] = z[j[u]];
        #pragma unroll
        for (int u = 0; u < 16; ++u) { a0 += v[u].x; a1 += v[u].y; }
    }
    for (; k < r1; ++k) {
        float2 zv = z[csr[k]];
        a0 += zv.x; a1 += zv.y;
    }
    float di = dinv[i];
    float g0 = di * a0, g1 = di * a1;
    float4 o;
    o.x = di * tanhf(fmaf(g0, W1[0], fmaf(g1, W1[4], b1[0])));
    o.y = di * tanhf(fmaf(g0, W1[1], fmaf(g1, W1[5], b1[1])));
    o.z = di * tanhf(fmaf(g0, W1[2], fmaf(g1, W1[6], b1[2])));
    o.w = di * tanhf(fmaf(g0, W1[3], fmaf(g1, W1[7], b1[3])));
    ((float4*)z2)[i] = o;
}

__global__ void gcn2(const int* __restrict__ rowptr, const unsigned* __restrict__ csr,
                     const float* __restrict__ z2, const float* __restrict__ W2,
                     const float* __restrict__ b2, const float* __restrict__ W3,
                     const float* __restrict__ dinv, float* __restrict__ z3, int N) {
    int i = blockIdx.x * blockDim.x + threadIdx.x;
    if (i >= N) return;
    int r0 = rowptr[i], r1 = rowptr[i + 1];
    float4 a = ((const float4*)z2)[i];
    const float4* z = (const float4*)z2;
    int k = r0;
    for (; k + 8 <= r1; k += 8) {
        unsigned j[8];
        #pragma unroll
        for (int u = 0; u < 8; ++u) j[u] = csr[k + u];
        float4 v[8];
        #pragma unroll
        for (int u = 0; u < 8; ++u) v[u] = z[j[u]];
        #pragma unroll
        for (int u = 0; u < 8; ++u) {
            a.x += v[u].x; a.y += v[u].y; a.z += v[u].z; a.w += v[u].w;
        }
    }
    for (; k < r1; ++k) {
        float4 zv = z[csr[k]];
        a.x += zv.x; a.y += zv.y; a.z += zv.z; a.w += zv.w;
    }
    float di = dinv[i];
    float g0 = di * a.x, g1 = di * a.y, g2 = di * a.z, g3 = di * a.w;
    float h[4];
    #pragma unroll
    for (int c = 0; c < 4; ++c)
        h[c] = tanhf(b2[c] + g0 * W2[c] + g1 * W2[4 + c] + g2 * W2[8 + c] + g3 * W2[12 + c]);
    float v0 = h[0] * W3[0] + h[1] * W3[2] + h[2] * W3[4] + h[3] * W3[6];
    float v1 = h[0] * W3[1] + h[1] * W3[3] + h[2] * W3[5] + h[3] * W3[7];
    ((float2*)z3)[i] = make_float2(v0 * di, v1 * di);
}

__global__ void gcn3(const int* __restrict__ rowptr, const unsigned* __restrict__ csr,
                     const float* __restrict__ z3, const float* __restrict__ b3,
                     const float* __restrict__ dinv, float* __restrict__ out, int N) {
    int i = blockIdx.x * blockDim.x + threadIdx.x;
    if (i >= N) return;
    int r0 = rowptr[i], r1 = rowptr[i + 1];
    float2 zi = ((const float2*)z3)[i];
    float a0 = zi.x, a1 = zi.y;
    const float2* z = (const float2*)z3;
    int k = r0;
    for (; k + 16 <= r1; k += 16) {
        unsigned j[16];
        #pragma unroll
        for (int u = 0; u < 16; ++u) j[u] = csr[k + u];
        float2 v[16];
        #pragma unroll
        for (int u = 0; u < 16; ++u) v[u] = z[j[u]];
        #pragma unroll
        for (int u = 0; u < 16; ++u) { a0 += v[u].x; a1 += v[u].y; }
    }
    for (; k < r1; ++k) {
        float2 zv = z[csr[k]];
        a0 += zv.x; a1 += zv.y;
    }
    float di = dinv[i];
    ((float2*)out)[i] = make_float2(fmaf(di, a0, b3[0]), fmaf(di, a1, b3[1]));
}

extern "C" void kernel_launch(void* const* d_in, const int* in_sizes, int n_in,
                              void* d_out, int out_size, void* d_ws, size_t ws_size,
                              hipStream_t stream) {
    const float* x  = (const float*)d_in[0];
    const int*   ei = (const int*)d_in[1];
    const float* W1 = (const float*)d_in[2];
    const float* b1 = (const float*)d_in[3];
    const float* W2 = (const float*)d_in[4];
    const float* b2 = (const float*)d_in[5];
    const float* W3 = (const float*)d_in[6];
    const float* b3 = (const float*)d_in[7];
    float* out = (float*)d_out;

    const int N = in_sizes[0] / 2;
    const int E = in_sizes[1] / 2;
    const int* src = ei;
    const int* dst = ei + E;

    const int B   = (N + NPB - 1) >> NPB_BITS;       // 489 buckets of 1024 nodes
    const int ntB = (E + T_TILE - 1) / T_TILE;       // 489 tiles of 32K edges
    const int mlen = B * ntB;                        // ~239K
    const int NB = (mlen + 1023) / 1024;             // ~234

    // ws layout (256B-aligned), ~149MB total
    auto align = [](size_t o) { return (o + 255) & ~(size_t)255; };
    char* wbase = (char*)d_ws;
    size_t off = 0;
    float*    dinv   = (float*)(wbase + off);    off = align(off + (size_t)N * 4);
    float*    z1     = (float*)(wbase + off);    off = align(off + (size_t)2 * N * 4);
    float*    z2     = (float*)(wbase + off);    off = align(off + (size_t)4 * N * 4);
    float*    z3     = (float*)(wbase + off);    off = align(off + (size_t)2 * N * 4);
    int*      rowptr = (int*)(wbase + off);      off = align(off + (size_t)(N + 1) * 4);
    int*      bsum   = (int*)(wbase + off);      off = align(off + (size_t)1024 * 4);
    int*      baseD  = (int*)(wbase + off);      off = align(off + (size_t)(B + 1) * 4);
    int*      cntD   = (int*)(wbase + off);      off = align(off + (size_t)mlen * 4);
    unsigned* pk     = (unsigned*)(wbase + off); off = align(off + (size_t)E * 4);
    unsigned* csr    = (unsigned*)(wbase + off); off = align(off + (size_t)E * 4);

    dim3 blk(TPB);
    dim3 gN((N + TPB - 1) / TPB);
    tilecount<<<dim3(ntB), blk, 0, stream>>>(dst, cntD, ntB, E, B);
    scan_k1<<<dim3(NB), blk, 0, stream>>>(cntD, bsum, mlen);
    scan_k2<<<dim3(1), dim3(1024), 0, stream>>>(bsum, NB);
    scan_k3<<<dim3(NB), blk, 0, stream>>>(cntD, bsum, mlen);
    extract_bases<<<dim3(1), dim3(1024), 0, stream>>>(cntD, ntB, B, baseD, E);
    scatterD<<<dim3(256), blk, 0, stream>>>(dst, src, cntD, pk, ntB, E, B);
    sortbuild<<<dim3(B), blk, 0, stream>>>(baseD, pk, x, rowptr, dinv, z1, csr, N, B);
    gcn1<<<gN, blk, 0, stream>>>(rowptr, csr, z1, W1, b1, dinv, z2, N);
    gcn2<<<gN, blk, 0, stream>>>(rowptr, csr, z2, W2, b2, W3, dinv, z3, N);
    gcn3<<<gN, blk, 0, stream>>>(rowptr, csr, z3, b3, dinv, out, N);
}

// Round 12
// 928.115 us; speedup vs baseline: 1.3269x; 1.0859x over previous
//
#include <hip/hip_runtime.h>

// GCN 3-layer. Two-pass build: scatter1 -> 123 superbuckets of 4096 nodes
// (123 cursors/block, runs=17 lines/tile, dirty ~0.5MB/XCD -> full-line
// write-back; R11's 489-cursor scatterD hit 245MB WRITE = partial-line
// write-through at ~1.1TB/s), then buildfine: block per 1024-node fine bucket
// (4 per superbucket) streams its superbucket region twice (4x L3-read amp),
// in-LDS counting sort of matching edges -> csr (coalesced staged writeback)
// + rowptr/dinv/z1 fused. csr_base via one ballot/64 edges (#edges with f<j).
// This deletes R11's sortbuild AND one scatter pass.
// Math per layer (input u): z = u*dinv; s_i = sum_{e:dst=i} z[src_e];
//   out_i = (dinv_i*(s_i + z_i)) @ W + b   (self-loop folds into s+z).
// pk1 = (dst&4095) | (src<<12)  (31 bits, N < 2^19). Layers: R3-proven
// thread-per-node unrolled gathers (zero atomics, full occupancy).

#define TPB 256
#define T_TILE 32768
#define SBB 12           // superbucket = 4096 nodes
#define NSB_MAX 128
#define FINE_BITS 10     // fine bucket = 1024 nodes, 4 per superbucket
#define EB_CAP 34048     // mean fine bucket 32.7K edges, +7 sigma

// ---------------- pass 0: per-tile superbucket histogram ----------------

__global__ void __launch_bounds__(512)
count1(const int* __restrict__ dst, int* __restrict__ cnt1, int ntB, int E, int SB) {
    __shared__ int hist[NSB_MAX];
    int blk = blockIdx.x, tid = threadIdx.x;
    if (tid < SB) hist[tid] = 0;
    __syncthreads();
    int base = blk * T_TILE;
    #pragma unroll 8
    for (int it = 0; it < T_TILE / 512; ++it) {
        int e = base + it * 512 + tid;
        if (e < E) atomicAdd(&hist[((unsigned)dst[e]) >> SBB], 1);
    }
    __syncthreads();
    if (tid < SB) cnt1[(size_t)tid * ntB + blk] = hist[tid];
}

// ---- 3-kernel exclusive scan over data[len] (in-place), 1024 elems/block ----
__global__ void scan_k1(const int* __restrict__ data, int* __restrict__ bsum, int len) {
    __shared__ int lds[TPB];
    int b = blockIdx.x, t = threadIdx.x;
    int base = b * 1024 + t * 4;
    int s = 0;
    #pragma unroll
    for (int j = 0; j < 4; ++j) { int i = base + j; if (i < len) s += data[i]; }
    lds[t] = s; __syncthreads();
    for (int off = 128; off > 0; off >>= 1) {
        if (t < off) lds[t] += lds[t + off];
        __syncthreads();
    }
    if (t == 0) bsum[b] = lds[0];
}

__global__ void scan_k2(int* __restrict__ bsum, int NB) {
    __shared__ int lds[1024];
    int t = threadIdx.x;
    int v = (t < NB) ? bsum[t] : 0;
    lds[t] = v; __syncthreads();
    for (int off = 1; off < 1024; off <<= 1) {
        int add = (t >= off) ? lds[t - off] : 0;
        __syncthreads();
        lds[t] += add;
        __syncthreads();
    }
    if (t < NB) bsum[t] = lds[t] - v;  // exclusive
}

__global__ void scan_k3(int* __restrict__ data, const int* __restrict__ bsum, int len) {
    __shared__ int lds[TPB];
    int b = blockIdx.x, t = threadIdx.x;
    int base = b * 1024 + t * 4;
    int v[4]; int s = 0;
    #pragma unroll
    for (int j = 0; j < 4; ++j) { int i = base + j; v[j] = (i < len) ? data[i] : 0; s += v[j]; }
    int orig = s;
    lds[t] = s; __syncthreads();
    for (int off = 1; off < 256; off <<= 1) {
        int add = (t >= off) ? lds[t - off] : 0;
        __syncthreads();
        lds[t] += add;
        __syncthreads();
    }
    int run = bsum[b] + lds[t] - orig;
    #pragma unroll
    for (int j = 0; j < 4; ++j) {
        int i = base + j;
        if (i < len) { data[i] = run; run += v[j]; }
    }
}

__global__ void bases_fix(const int* __restrict__ cnt1, int ntB, int SB,
                          int* __restrict__ bases1, int* __restrict__ rowptr,
                          int N, int E) {
    int t = threadIdx.x;
    if (t < SB) bases1[t] = cnt1[(size_t)t * ntB];
    if (t == 0) { bases1[SB] = E; rowptr[N] = E; }
}

// ---- pass 1: scatter into superbucket regions (clean write-back) ----
__global__ void __launch_bounds__(512)
scatter1(const int* __restrict__ dst, const int* __restrict__ src,
         const int* __restrict__ cnt1, unsigned* __restrict__ pk1,
         int ntB, int E, int SB) {
    __shared__ int basec[NSB_MAX];
    int blk = blockIdx.x, tid = threadIdx.x;
    if (tid < SB) basec[tid] = cnt1[(size_t)tid * ntB + blk];
    __syncthreads();
    int base = blk * T_TILE;
    #pragma unroll 8
    for (int it = 0; it < T_TILE / 512; ++it) {
        int e = base + it * 512 + tid;
        if (e < E) {
            unsigned d = (unsigned)dst[e];
            unsigned s = (unsigned)src[e];
            int pos = atomicAdd(&basec[d >> SBB], 1);
            pk1[pos] = (d & 4095u) | (s << SBB);
        }
    }
}

// ---- pass 2: fused fine+node sort. Block (sb,j) owns 1024-node fine bucket,
// streams superbucket region twice, emits csr + rowptr + dinv + z1. ----
__global__ void __launch_bounds__(1024)
buildfine(const int* __restrict__ bases1, const unsigned* __restrict__ pk1,
          const float* __restrict__ x, int* __restrict__ rowptr,
          float* __restrict__ dinv, float* __restrict__ z1,
          unsigned* __restrict__ csr, int N) {
    __shared__ int cnt[1024];
    __shared__ int tmp[1024];
    __shared__ int cur[1024];
    __shared__ unsigned eb[EB_CAP];
    __shared__ int redbase;
    int bid = blockIdx.x, tid = threadIdx.x;
    int sb = bid >> 2, j = bid & 3;
    int node0 = (sb << SBB) + (j << FINE_BITS);
    int ebeg = bases1[sb], eend = bases1[sb + 1];
    int n = eend - ebeg;
    cnt[tid] = 0;
    if (tid == 0) redbase = 0;
    __syncthreads();
    int lane = tid & 63;
    int myprev = 0;  // wave-uniform count of region edges with fine-id < j
    int k0 = 0;
    for (; k0 + 8192 <= n; k0 += 8192) {
        unsigned p[8];
        #pragma unroll
        for (int u = 0; u < 8; ++u) p[u] = pk1[ebeg + k0 + tid + u * 1024];
        #pragma unroll
        for (int u = 0; u < 8; ++u) {
            int f = (int)((p[u] >> FINE_BITS) & 3u);
            myprev += (int)__popcll(__ballot(f < j));
            if (f == j) atomicAdd(&cnt[p[u] & 1023u], 1);
        }
    }
    for (int kk = k0; kk < n; kk += 1024) {
        int k = kk + tid;
        bool valid = (k < n);
        unsigned p = valid ? pk1[ebeg + k] : 0u;
        int f = valid ? (int)((p >> FINE_BITS) & 3u) : 4;
        myprev += (int)__popcll(__ballot(valid && f < j));
        if (valid && f == j) atomicAdd(&cnt[p & 1023u], 1);
    }
    if (lane == 0 && myprev > 0) atomicAdd(&redbase, myprev);
    __syncthreads();
    int csr_base = ebeg + redbase;
    // block scan of cnt[1024]
    int c = cnt[tid];
    tmp[tid] = c; __syncthreads();
    for (int o = 1; o < 1024; o <<= 1) {
        int a = (tid >= o) ? tmp[tid - o] : 0;
        __syncthreads();
        tmp[tid] += a;
        __syncthreads();
    }
    int excl = tmp[tid] - c;
    int tot = tmp[1023];
    int i = node0 + tid;
    if (i < N) {
        rowptr[i] = csr_base + excl;
        float di = rsqrtf((float)c + 1.0f);
        dinv[i] = di;
        float2 xv = ((const float2*)x)[i];
        ((float2*)z1)[i] = make_float2(xv.x * di, xv.y * di);
    }
    cur[tid] = excl;  // bucket-relative cursor
    __syncthreads();
    if (tot <= EB_CAP) {
        k0 = 0;
        for (; k0 + 8192 <= n; k0 += 8192) {
            unsigned p[8];
            #pragma unroll
            for (int u = 0; u < 8; ++u) p[u] = pk1[ebeg + k0 + tid + u * 1024];
            #pragma unroll
            for (int u = 0; u < 8; ++u) {
                if (((p[u] >> FINE_BITS) & 3u) == (unsigned)j) {
                    int pos = atomicAdd(&cur[p[u] & 1023u], 1);
                    eb[pos] = p[u] >> SBB;
                }
            }
        }
        for (int k = k0 + tid; k < n; k += 1024) {
            unsigned p = pk1[ebeg + k];
            if (((p >> FINE_BITS) & 3u) == (unsigned)j) {
                int pos = atomicAdd(&cur[p & 1023u], 1);
                eb[pos] = p >> SBB;
            }
        }
        __syncthreads();
        for (int k = tid; k < tot; k += 1024) csr[csr_base + k] = eb[k];
    } else {
        // rare overflow: direct global placement (slow but correct)
        for (int k = tid; k < n; k += 1024) {
            unsigned p = pk1[ebeg + k];
            if (((p >> FINE_BITS) & 3u) == (unsigned)j) {
                int pos = atomicAdd(&cur[p & 1023u], 1);
                csr[csr_base + pos] = p >> SBB;
            }
        }
    }
}

// ---------------- GCN layers (R3-proven unrolled gathers) ----------------

__global__ void gcn1(const int* __restrict__ rowptr, const unsigned* __restrict__ csr,
                     const float* __restrict__ z1, const float* __restrict__ W1,
                     const float* __restrict__ b1, const float* __restrict__ dinv,
                     float* __restrict__ z2, int N) {
    int i = blockIdx.x * blockDim.x + threadIdx.x;
    if (i >= N) return;
    int r0 = rowptr[i], r1 = rowptr[i + 1];
    float2 zi = ((const float2*)z1)[i];
    float a0 = zi.x, a1 = zi.y;
    const float2* z = (const float2*)z1;
    int k = r0;
    for (; k + 16 <= r1; k += 16) {
        unsigned j[16];
        #pragma unroll
        for (int u = 0; u < 16; ++u) j[u] = csr[k + u];
        float2 v[16];
        #pragma unroll
        for (int u = 0; u < 16; ++u) v[u] = z[j[u]];
        #pragma unroll
        for (int u = 0; u < 16; ++u) { a0 += v[u].x; a1 += v[u].y; }
    }
    for (; k < r1; ++k) {
        float2 zv = z[csr[k]];
        a0 += zv.x; a1 += zv.y;
    }
    float di = dinv[i];
    float g0 = di * a0, g1 = di * a1;
    float4 o;
    o.x = di * tanhf(fmaf(g0, W1[0], fmaf(g1, W1[4], b1[0])));
    o.y = di * tanhf(fmaf(g0, W1[1], fmaf(g1, W1[5], b1[1])));
    o.z = di * tanhf(fmaf(g0, W1[2], fmaf(g1, W1[6], b1[2])));
    o.w = di * tanhf(fmaf(g0, W1[3], fmaf(g1, W1[7], b1[3])));
    ((float4*)z2)[i] = o;
}

__global__ void gcn2(const int* __restrict__ rowptr, const unsigned* __restrict__ csr,
                     const float* __restrict__ z2, const float* __restrict__ W2,
                     const float* __restrict__ b2, const float* __restrict__ W3,
                     const float* __restrict__ dinv, float* __restrict__ z3, int N) {
    int i = blockIdx.x * blockDim.x + threadIdx.x;
    if (i >= N) return;
    int r0 = rowptr[i], r1 = rowptr[i + 1];
    float4 a = ((const float4*)z2)[i];
    const float4* z = (const float4*)z2;
    int k = r0;
    for (; k + 8 <= r1; k += 8) {
        unsigned j[8];
        #pragma unroll
        for (int u = 0; u < 8; ++u) j[u] = csr[k + u];
        float4 v[8];
        #pragma unroll
        for (int u = 0; u < 8; ++u) v[u] = z[j[u]];
        #pragma unroll
        for (int u = 0; u < 8; ++u) {
            a.x += v[u].x; a.y += v[u].y; a.z += v[u].z; a.w += v[u].w;
        }
    }
    for (; k < r1; ++k) {
        float4 zv = z[csr[k]];
        a.x += zv.x; a.y += zv.y; a.z += zv.z; a.w += zv.w;
    }
    float di = dinv[i];
    float g0 = di * a.x, g1 = di * a.y, g2 = di * a.z, g3 = di * a.w;
    float h[4];
    #pragma unroll
    for (int c = 0; c < 4; ++c)
        h[c] = tanhf(b2[c] + g0 * W2[c] + g1 * W2[4 + c] + g2 * W2[8 + c] + g3 * W2[12 + c]);
    float v0 = h[0] * W3[0] + h[1] * W3[2] + h[2] * W3[4] + h[3] * W3[6];
    float v1 = h[0] * W3[1] + h[1] * W3[3] + h[2] * W3[5] + h[3] * W3[7];
    ((float2*)z3)[i] = make_float2(v0 * di, v1 * di);
}

__global__ void gcn3(const int* __restrict__ rowptr, const unsigned* __restrict__ csr,
                     const float* __restrict__ z3, const float* __restrict__ b3,
                     const float* __restrict__ dinv, float* __restrict__ out, int N) {
    int i = blockIdx.x * blockDim.x + threadIdx.x;
    if (i >= N) return;
    int r0 = rowptr[i], r1 = rowptr[i + 1];
    float2 zi = ((const float2*)z3)[i];
    float a0 = zi.x, a1 = zi.y;
    const float2* z = (const float2*)z3;
    int k = r0;
    for (; k + 16 <= r1; k += 16) {
        unsigned j[16];
        #pragma unroll
        for (int u = 0; u < 16; ++u) j[u] = csr[k + u];
        float2 v[16];
        #pragma unroll
        for (int u = 0; u < 16; ++u) v[u] = z[j[u]];
        #pragma unroll
        for (int u = 0; u < 16; ++u) { a0 += v[u].x; a1 += v[u].y; }
    }
    for (; k < r1; ++k) {
        float2 zv = z[csr[k]];
        a0 += zv.x; a1 += zv.y;
    }
    float di = dinv[i];
    ((float2*)out)[i] = make_float2(fmaf(di, a0, b3[0]), fmaf(di, a1, b3[1]));
}

extern "C" void kernel_launch(void* const* d_in, const int* in_sizes, int n_in,
                              void* d_out, int out_size, void* d_ws, size_t ws_size,
                              hipStream_t stream) {
    const float* x  = (const float*)d_in[0];
    const int*   ei = (const int*)d_in[1];
    const float* W1 = (const float*)d_in[2];
    const float* b1 = (const float*)d_in[3];
    const float* W2 = (const float*)d_in[4];
    const float* b2 = (const float*)d_in[5];
    const float* W3 = (const float*)d_in[6];
    const float* b3 = (const float*)d_in[7];
    float* out = (float*)d_out;

    const int N = in_sizes[0] / 2;
    const int E = in_sizes[1] / 2;
    const int* src = ei;
    const int* dst = ei + E;

    const int SB  = (N + (1 << SBB) - 1) >> SBB;     // 123 superbuckets
    const int ntB = (E + T_TILE - 1) / T_TILE;       // 489 tiles of 32K edges
    const int mlen = SB * ntB;                       // ~60K
    const int NB = (mlen + 1023) / 1024;             // ~59

    // ws layout (256B-aligned), ~146MB total
    auto align = [](size_t o) { return (o + 255) & ~(size_t)255; };
    char* wbase = (char*)d_ws;
    size_t off = 0;
    float*    dinv   = (float*)(wbase + off);    off = align(off + (size_t)N * 4);
    float*    z1     = (float*)(wbase + off);    off = align(off + (size_t)2 * N * 4);
    float*    z2     = (float*)(wbase + off);    off = align(off + (size_t)4 * N * 4);
    float*    z3     = (float*)(wbase + off);    off = align(off + (size_t)2 * N * 4);
    int*      rowptr = (int*)(wbase + off);      off = align(off + (size_t)(N + 1) * 4);
    int*      bsum   = (int*)(wbase + off);      off = align(off + (size_t)1024 * 4);
    int*      bases1 = (int*)(wbase + off);      off = align(off + (size_t)(SB + 1) * 4);
    int*      cnt1   = (int*)(wbase + off);      off = align(off + (size_t)mlen * 4);
    unsigned* pk1    = (unsigned*)(wbase + off); off = align(off + (size_t)E * 4);
    unsigned* csr    = (unsigned*)(wbase + off); off = align(off + (size_t)E * 4);

    dim3 gN((N + TPB - 1) / TPB);
    count1<<<dim3(ntB), dim3(512), 0, stream>>>(dst, cnt1, ntB, E, SB);
    scan_k1<<<dim3(NB), dim3(TPB), 0, stream>>>(cnt1, bsum, mlen);
    scan_k2<<<dim3(1), dim3(1024), 0, stream>>>(bsum, NB);
    scan_k3<<<dim3(NB), dim3(TPB), 0, stream>>>(cnt1, bsum, mlen);
    bases_fix<<<dim3(1), dim3(256), 0, stream>>>(cnt1, ntB, SB, bases1, rowptr, N, E);
    scatter1<<<dim3(ntB), dim3(512), 0, stream>>>(dst, src, cnt1, pk1, ntB, E, SB);
    buildfine<<<dim3(SB * 4), dim3(1024), 0, stream>>>(bases1, pk1, x, rowptr, dinv,
                                                       z1, csr, N);
    gcn1<<<gN, dim3(TPB), 0, stream>>>(rowptr, csr, z1, W1, b1, dinv, z2, N);
    gcn2<<<gN, dim3(TPB), 0, stream>>>(rowptr, csr, z2, W2, b2, W3, dinv, z3, N);
    gcn3<<<gN, dim3(TPB), 0, stream>>>(rowptr, csr, z3, b3, dinv, out, N);
}

// Round 13
// 872.226 us; speedup vs baseline: 1.4119x; 1.0641x over previous
//
#include <hip/hip_runtime.h>
#include <hip/hip_fp16.h>

// GCN 3-layer. Two-pass build (R12-proven): scatter1 -> 123 superbuckets of
// 4096 nodes (clean full-line write-back), buildfine -> block per 1024-node
// fine bucket, in-LDS counting sort -> csr + rowptr/dinv/z1 fused.
// Layers: thread-per-node unrolled gathers (zero atomics).
// R13 change: z2 stored as 4xfp16 (8B/node) -> gather table 4MB fits per-XCD
// L2 (R12: fp32 z2 = 8MB table -> gcn2 FETCH 785MB, 49B/edge, 216us
// gather-traffic bound). csr streams use non-temporal loads so the 64MB/layer
// index stream doesn't evict z-tables from L2. fp16 error budget: ~1e-4
// end-to-end (absmax 1.2e-4 -> ~3e-4, threshold 1e-3).
// Math per layer (input u): z = u*dinv; s_i = sum_{e:dst=i} z[src_e];
//   out_i = (dinv_i*(s_i + z_i)) @ W + b   (self-loop folds into s+z).
// pk1 = (dst&4095) | (src<<12)  (31 bits, N < 2^19).

#define TPB 256
#define T_TILE 32768
#define SBB 12           // superbucket = 4096 nodes
#define NSB_MAX 128
#define FINE_BITS 10     // fine bucket = 1024 nodes, 4 per superbucket
#define EB_CAP 34048     // mean fine bucket 32.7K edges, +7 sigma

// ---------------- pass 0: per-tile superbucket histogram ----------------

__global__ void __launch_bounds__(512)
count1(const int* __restrict__ dst, int* __restrict__ cnt1, int ntB, int E, int SB) {
    __shared__ int hist[NSB_MAX];
    int blk = blockIdx.x, tid = threadIdx.x;
    if (tid < SB) hist[tid] = 0;
    __syncthreads();
    int base = blk * T_TILE;
    #pragma unroll 8
    for (int it = 0; it < T_TILE / 512; ++it) {
        int e = base + it * 512 + tid;
        if (e < E) atomicAdd(&hist[((unsigned)dst[e]) >> SBB], 1);
    }
    __syncthreads();
    if (tid < SB) cnt1[(size_t)tid * ntB + blk] = hist[tid];
}

// ---- 3-kernel exclusive scan over data[len] (in-place), 1024 elems/block ----
__global__ void scan_k1(const int* __restrict__ data, int* __restrict__ bsum, int len) {
    __shared__ int lds[TPB];
    int b = blockIdx.x, t = threadIdx.x;
    int base = b * 1024 + t * 4;
    int s = 0;
    #pragma unroll
    for (int j = 0; j < 4; ++j) { int i = base + j; if (i < len) s += data[i]; }
    lds[t] = s; __syncthreads();
    for (int off = 128; off > 0; off >>= 1) {
        if (t < off) lds[t] += lds[t + off];
        __syncthreads();
    }
    if (t == 0) bsum[b] = lds[0];
}

__global__ void scan_k2(int* __restrict__ bsum, int NB) {
    __shared__ int lds[1024];
    int t = threadIdx.x;
    int v = (t < NB) ? bsum[t] : 0;
    lds[t] = v; __syncthreads();
    for (int off = 1; off < 1024; off <<= 1) {
        int add = (t >= off) ? lds[t - off] : 0;
        __syncthreads();
        lds[t] += add;
        __syncthreads();
    }
    if (t < NB) bsum[t] = lds[t] - v;  // exclusive
}

__global__ void scan_k3(int* __restrict__ data, const int* __restrict__ bsum, int len) {
    __shared__ int lds[TPB];
    int b = blockIdx.x, t = threadIdx.x;
    int base = b * 1024 + t * 4;
    int v[4]; int s = 0;
    #pragma unroll
    for (int j = 0; j < 4; ++j) { int i = base + j; v[j] = (i < len) ? data[i] : 0; s += v[j]; }
    int orig = s;
    lds[t] = s; __syncthreads();
    for (int off = 1; off < 256; off <<= 1) {
        int add = (t >= off) ? lds[t - off] : 0;
        __syncthreads();
        lds[t] += add;
        __syncthreads();
    }
    int run = bsum[b] + lds[t] - orig;
    #pragma unroll
    for (int j = 0; j < 4; ++j) {
        int i = base + j;
        if (i < len) { data[i] = run; run += v[j]; }
    }
}

__global__ void bases_fix(const int* __restrict__ cnt1, int ntB, int SB,
                          int* __restrict__ bases1, int* __restrict__ rowptr,
                          int N, int E) {
    int t = threadIdx.x;
    if (t < SB) bases1[t] = cnt1[(size_t)t * ntB];
    if (t == 0) { bases1[SB] = E; rowptr[N] = E; }
}

// ---- pass 1: scatter into superbucket regions (clean write-back) ----
__global__ void __launch_bounds__(512)
scatter1(const int* __restrict__ dst, const int* __restrict__ src,
         const int* __restrict__ cnt1, unsigned* __restrict__ pk1,
         int ntB, int E, int SB) {
    __shared__ int basec[NSB_MAX];
    int blk = blockIdx.x, tid = threadIdx.x;
    if (tid < SB) basec[tid] = cnt1[(size_t)tid * ntB + blk];
    __syncthreads();
    int base = blk * T_TILE;
    #pragma unroll 8
    for (int it = 0; it < T_TILE / 512; ++it) {
        int e = base + it * 512 + tid;
        if (e < E) {
            unsigned d = (unsigned)dst[e];
            unsigned s = (unsigned)src[e];
            int pos = atomicAdd(&basec[d >> SBB], 1);
            pk1[pos] = (d & 4095u) | (s << SBB);
        }
    }
}

// ---- pass 2: fused fine+node sort -> csr + rowptr + dinv + z1 ----
__global__ void __launch_bounds__(1024)
buildfine(const int* __restrict__ bases1, const unsigned* __restrict__ pk1,
          const float* __restrict__ x, int* __restrict__ rowptr,
          float* __restrict__ dinv, float* __restrict__ z1,
          unsigned* __restrict__ csr, int N) {
    __shared__ int cnt[1024];
    __shared__ int tmp[1024];
    __shared__ int cur[1024];
    __shared__ unsigned eb[EB_CAP];
    __shared__ int redbase;
    int bid = blockIdx.x, tid = threadIdx.x;
    int sb = bid >> 2, j = bid & 3;
    int node0 = (sb << SBB) + (j << FINE_BITS);
    int ebeg = bases1[sb], eend = bases1[sb + 1];
    int n = eend - ebeg;
    cnt[tid] = 0;
    if (tid == 0) redbase = 0;
    __syncthreads();
    int lane = tid & 63;
    int myprev = 0;  // wave count of region edges with fine-id < j
    int k0 = 0;
    for (; k0 + 8192 <= n; k0 += 8192) {
        unsigned p[8];
        #pragma unroll
        for (int u = 0; u < 8; ++u) p[u] = pk1[ebeg + k0 + tid + u * 1024];
        #pragma unroll
        for (int u = 0; u < 8; ++u) {
            int f = (int)((p[u] >> FINE_BITS) & 3u);
            myprev += (int)__popcll(__ballot(f < j));
            if (f == j) atomicAdd(&cnt[p[u] & 1023u], 1);
        }
    }
    for (int kk = k0; kk < n; kk += 1024) {
        int k = kk + tid;
        bool valid = (k < n);
        unsigned p = valid ? pk1[ebeg + k] : 0u;
        int f = valid ? (int)((p >> FINE_BITS) & 3u) : 4;
        myprev += (int)__popcll(__ballot(valid && f < j));
        if (valid && f == j) atomicAdd(&cnt[p & 1023u], 1);
    }
    if (lane == 0 && myprev > 0) atomicAdd(&redbase, myprev);
    __syncthreads();
    int csr_base = ebeg + redbase;
    int c = cnt[tid];
    tmp[tid] = c; __syncthreads();
    for (int o = 1; o < 1024; o <<= 1) {
        int a = (tid >= o) ? tmp[tid - o] : 0;
        __syncthreads();
        tmp[tid] += a;
        __syncthreads();
    }
    int excl = tmp[tid] - c;
    int tot = tmp[1023];
    int i = node0 + tid;
    if (i < N) {
        rowptr[i] = csr_base + excl;
        float di = rsqrtf((float)c + 1.0f);
        dinv[i] = di;
        float2 xv = ((const float2*)x)[i];
        ((float2*)z1)[i] = make_float2(xv.x * di, xv.y * di);
    }
    cur[tid] = excl;
    __syncthreads();
    if (tot <= EB_CAP) {
        k0 = 0;
        for (; k0 + 8192 <= n; k0 += 8192) {
            unsigned p[8];
            #pragma unroll
            for (int u = 0; u < 8; ++u) p[u] = pk1[ebeg + k0 + tid + u * 1024];
            #pragma unroll
            for (int u = 0; u < 8; ++u) {
                if (((p[u] >> FINE_BITS) & 3u) == (unsigned)j) {
                    int pos = atomicAdd(&cur[p[u] & 1023u], 1);
                    eb[pos] = p[u] >> SBB;
                }
            }
        }
        for (int k = k0 + tid; k < n; k += 1024) {
            unsigned p = pk1[ebeg + k];
            if (((p >> FINE_BITS) & 3u) == (unsigned)j) {
                int pos = atomicAdd(&cur[p & 1023u], 1);
                eb[pos] = p >> SBB;
            }
        }
        __syncthreads();
        for (int k = tid; k < tot; k += 1024) csr[csr_base + k] = eb[k];
    } else {
        for (int k = tid; k < n; k += 1024) {
            unsigned p = pk1[ebeg + k];
            if (((p >> FINE_BITS) & 3u) == (unsigned)j) {
                int pos = atomicAdd(&cur[p & 1023u], 1);
                csr[csr_base + pos] = p >> SBB;
            }
        }
    }
}

// ---------------- GCN layers ----------------

__global__ void gcn1(const int* __restrict__ rowptr, const unsigned* __restrict__ csr,
                     const float* __restrict__ z1, const float* __restrict__ W1,
                     const float* __restrict__ b1, const float* __restrict__ dinv,
                     uint2* __restrict__ z2h, int N) {
    int i = blockIdx.x * blockDim.x + threadIdx.x;
    if (i >= N) return;
    int r0 = rowptr[i], r1 = rowptr[i + 1];
    float2 zi = ((const float2*)z1)[i];
    float a0 = zi.x, a1 = zi.y;
    const float2* z = (const float2*)z1;
    int k = r0;
    for (; k + 16 <= r1; k += 16) {
        unsigned j[16];
        #pragma unroll
        for (int u = 0; u < 16; ++u) j[u] = __builtin_nontemporal_load(&csr[k + u]);
        float2 v[16];
        #pragma unroll
        for (int u = 0; u < 16; ++u) v[u] = z[j[u]];
        #pragma unroll
        for (int u = 0; u < 16; ++u) { a0 += v[u].x; a1 += v[u].y; }
    }
    for (; k < r1; ++k) {
        float2 zv = z[csr[k]];
        a0 += zv.x; a1 += zv.y;
    }
    float di = dinv[i];
    float g0 = di * a0, g1 = di * a1;
    float o0 = di * tanhf(fmaf(g0, W1[0], fmaf(g1, W1[4], b1[0])));
    float o1 = di * tanhf(fmaf(g0, W1[1], fmaf(g1, W1[5], b1[1])));
    float o2 = di * tanhf(fmaf(g0, W1[2], fmaf(g1, W1[6], b1[2])));
    float o3 = di * tanhf(fmaf(g0, W1[3], fmaf(g1, W1[7], b1[3])));
    __half2 ha = __floats2half2_rn(o0, o1);
    __half2 hb = __floats2half2_rn(o2, o3);
    uint2 packed;
    packed.x = *(unsigned*)&ha;
    packed.y = *(unsigned*)&hb;
    z2h[i] = packed;
}

__global__ void gcn2(const int* __restrict__ rowptr, const unsigned* __restrict__ csr,
                     const uint2* __restrict__ z2h, const float* __restrict__ W2,
                     const float* __restrict__ b2, const float* __restrict__ W3,
                     const float* __restrict__ dinv, float* __restrict__ z3, int N) {
    int i = blockIdx.x * blockDim.x + threadIdx.x;
    if (i >= N) return;
    int r0 = rowptr[i], r1 = rowptr[i + 1];
    float a0, a1, a2, a3;
    {
        uint2 raw = z2h[i];
        float2 f01 = __half22float2(*(__half2*)&raw.x);
        float2 f23 = __half22float2(*(__half2*)&raw.y);
        a0 = f01.x; a1 = f01.y; a2 = f23.x; a3 = f23.y;
    }
    int k = r0;
    for (; k + 8 <= r1; k += 8) {
        unsigned j[8];
        #pragma unroll
        for (int u = 0; u < 8; ++u) j[u] = __builtin_nontemporal_load(&csr[k + u]);
        uint2 raw[8];
        #pragma unroll
        for (int u = 0; u < 8; ++u) raw[u] = z2h[j[u]];
        #pragma unroll
        for (int u = 0; u < 8; ++u) {
            float2 f01 = __half22float2(*(__half2*)&raw[u].x);
            float2 f23 = __half22float2(*(__half2*)&raw[u].y);
            a0 += f01.x; a1 += f01.y; a2 += f23.x; a3 += f23.y;
        }
    }
    for (; k < r1; ++k) {
        uint2 raw = z2h[csr[k]];
        float2 f01 = __half22float2(*(__half2*)&raw.x);
        float2 f23 = __half22float2(*(__half2*)&raw.y);
        a0 += f01.x; a1 += f01.y; a2 += f23.x; a3 += f23.y;
    }
    float di = dinv[i];
    float g0 = di * a0, g1 = di * a1, g2 = di * a2, g3 = di * a3;
    float h[4];
    #pragma unroll
    for (int c = 0; c < 4; ++c)
        h[c] = tanhf(b2[c] + g0 * W2[c] + g1 * W2[4 + c] + g2 * W2[8 + c] + g3 * W2[12 + c]);
    float v0 = h[0] * W3[0] + h[1] * W3[2] + h[2] * W3[4] + h[3] * W3[6];
    float v1 = h[0] * W3[1] + h[1] * W3[3] + h[2] * W3[5] + h[3] * W3[7];
    ((float2*)z3)[i] = make_float2(v0 * di, v1 * di);
}

__global__ void gcn3(const int* __restrict__ rowptr, const unsigned* __restrict__ csr,
                     const float* __restrict__ z3, const float* __restrict__ b3,
                     const float* __restrict__ dinv, float* __restrict__ out, int N) {
    int i = blockIdx.x * blockDim.x + threadIdx.x;
    if (i >= N) return;
    int r0 = rowptr[i], r1 = rowptr[i + 1];
    float2 zi = ((const float2*)z3)[i];
    float a0 = zi.x, a1 = zi.y;
    const float2* z = (const float2*)z3;
    int k = r0;
    for (; k + 16 <= r1; k += 16) {
        unsigned j[16];
        #pragma unroll
        for (int u = 0; u < 16; ++u) j[u] = __builtin_nontemporal_load(&csr[k + u]);
        float2 v[16];
        #pragma unroll
        for (int u = 0; u < 16; ++u) v[u] = z[j[u]];
        #pragma unroll
        for (int u = 0; u < 16; ++u) { a0 += v[u].x; a1 += v[u].y; }
    }
    for (; k < r1; ++k) {
        float2 zv = z[csr[k]];
        a0 += zv.x; a1 += zv.y;
    }
    float di = dinv[i];
    ((float2*)out)[i] = make_float2(fmaf(di, a0, b3[0]), fmaf(di, a1, b3[1]));
}

extern "C" void kernel_launch(void* const* d_in, const int* in_sizes, int n_in,
                              void* d_out, int out_size, void* d_ws, size_t ws_size,
                              hipStream_t stream) {
    const float* x  = (const float*)d_in[0];
    const int*   ei = (const int*)d_in[1];
    const float* W1 = (const float*)d_in[2];
    const float* b1 = (const float*)d_in[3];
    const float* W2 = (const float*)d_in[4];
    const float* b2 = (const float*)d_in[5];
    const float* W3 = (const float*)d_in[6];
    const float* b3 = (const float*)d_in[7];
    float* out = (float*)d_out;

    const int N = in_sizes[0] / 2;
    const int E = in_sizes[1] / 2;
    const int* src = ei;
    const int* dst = ei + E;

    const int SB  = (N + (1 << SBB) - 1) >> SBB;     // 123 superbuckets
    const int ntB = (E + T_TILE - 1) / T_TILE;       // 489 tiles of 32K edges
    const int mlen = SB * ntB;                       // ~60K
    const int NB = (mlen + 1023) / 1024;             // ~59

    // ws layout (256B-aligned)
    auto align = [](size_t o) { return (o + 255) & ~(size_t)255; };
    char* wbase = (char*)d_ws;
    size_t off = 0;
    float*    dinv   = (float*)(wbase + off);    off = align(off + (size_t)N * 4);
    float*    z1     = (float*)(wbase + off);    off = align(off + (size_t)2 * N * 4);
    uint2*    z2h    = (uint2*)(wbase + off);    off = align(off + (size_t)N * 8);
    float*    z3     = (float*)(wbase + off);    off = align(off + (size_t)2 * N * 4);
    int*      rowptr = (int*)(wbase + off);      off = align(off + (size_t)(N + 1) * 4);
    int*      bsum   = (int*)(wbase + off);      off = align(off + (size_t)1024 * 4);
    int*      bases1 = (int*)(wbase + off);      off = align(off + (size_t)(SB + 1) * 4);
    int*      cnt1   = (int*)(wbase + off);      off = align(off + (size_t)mlen * 4);
    unsigned* pk1    = (unsigned*)(wbase + off); off = align(off + (size_t)E * 4);
    unsigned* csr    = (unsigned*)(wbase + off); off = align(off + (size_t)E * 4);

    dim3 gN((N + TPB - 1) / TPB);
    count1<<<dim3(ntB), dim3(512), 0, stream>>>(dst, cnt1, ntB, E, SB);
    scan_k1<<<dim3(NB), dim3(TPB), 0, stream>>>(cnt1, bsum, mlen);
    scan_k2<<<dim3(1), dim3(1024), 0, stream>>>(bsum, NB);
    scan_k3<<<dim3(NB), dim3(TPB), 0, stream>>>(cnt1, bsum, mlen);
    bases_fix<<<dim3(1), dim3(256), 0, stream>>>(cnt1, ntB, SB, bases1, rowptr, N, E);
    scatter1<<<dim3(ntB), dim3(512), 0, stream>>>(dst, src, cnt1, pk1, ntB, E, SB);
    buildfine<<<dim3(SB * 4), dim3(1024), 0, stream>>>(bases1, pk1, x, rowptr, dinv,
                                                       z1, csr, N);
    gcn1<<<gN, dim3(TPB), 0, stream>>>(rowptr, csr, z1, W1, b1, dinv, z2h, N);
    gcn2<<<gN, dim3(TPB), 0, stream>>>(rowptr, csr, z2h, W2, b2, W3, dinv, z3, N);
    gcn3<<<gN, dim3(TPB), 0, stream>>>(rowptr, csr, z3, b3, dinv, out, N);
}